// Round 13
// baseline (298.223 us; speedup 1.0000x reference)
//
#include <hip/hip_runtime.h>
#include <cstdint>

// ---------------------------------------------------------------------------
// RegionModel R25: conv12 re-tiled to 2-out-row blocks -> 4 blocks/CU.
// R24 = 284us best. Hard bound from R23 profile: conv3dir2 < 69us; residual
// implies ~60-90us fixed harness overhead (poison fills in timed region).
// conv12 (104us) is MLP-bound: per stage phase each thread has ~5 loads in
// flight; 12 waves/CU x ~5 = 64 outstanding @ ~900cy HBM latency = the
// measured 1.4 TB/s. Throughput scales with resident waves.
// R25: block = 2 conv2 rows x 32 px: h1T [5][4][66][8] = 21.1KB, imgT 11
// rows = 14.8KB (single-phase; two-phase/T14 machinery deleted). LDS 36.3KB
// -> bounds(256,4) = 16 waves/CU (+33% MLP). Grid (2,32,128) = 8192 blocks.
// head_k de-serialized (float4 + dual accumulators). conv3dir2/setup kept.
// ---------------------------------------------------------------------------

typedef __attribute__((ext_vector_type(8))) short short8;
typedef __attribute__((ext_vector_type(4))) float floatx4;
typedef __attribute__((ext_vector_type(4))) unsigned short ushort4v;
typedef __attribute__((ext_vector_type(4))) float float4v;

__device__ inline unsigned short f2bf(float f) {
  union { float f; unsigned u; } x;
  x.f = f;
  unsigned u = x.u;
  u += 0x7FFFu + ((u >> 16) & 1u);  // round-to-nearest-even
  return (unsigned short)(u >> 16);
}

// Fused setup: block 0 = prep (region decode + feat zero); remaining blocks
// cover pack1 | packT2 | packT3 | h2p halo as one linear index space.
__global__ __launch_bounds__(256) void setup_k(
    const int* __restrict__ rp, int* __restrict__ rout, float* __restrict__ feat,
    const float* __restrict__ w1, unsigned short* __restrict__ w1p,
    const float* __restrict__ w2, unsigned short* __restrict__ w2p,
    const float* __restrict__ w3, unsigned short* __restrict__ w3p,
    unsigned short* __restrict__ h2p, int nhalo) {
  const int tid = threadIdx.x;
  if (blockIdx.x == 0) {
    __shared__ int is64;
    if (tid < 64) {  // wave 0: parallel probe of odd words
      int v = rp[2 * tid + 1];
      unsigned long long ball = __ballot(v != 0);
      if (tid == 0) is64 = (ball == 0ULL) ? 1 : 0;
    }
    __syncthreads();
    if (tid < 128) {
      int r = is64 ? rp[2 * tid] : rp[tid];
      rout[tid] = r & 7;
      float* fr = feat + tid * 128;
      for (int j = 0; j < 128; ++j) fr[j] = 0.f;
    }
    return;
  }
  int t = (blockIdx.x - 1) * 256 + tid;
  if (t < 16384) {
    int j = t & 7, lane = (t >> 3) & 63, mt = (t >> 9) & 1, kg = (t >> 10) & 1,
        r = t >> 11;
    int oc = mt * 16 + (lane & 15);
    int q = (lane >> 4) & 3;
    int row = kg * 2 + (q >> 1);
    int idx = (q & 1) * 8 + j;
    int kx = idx >> 2, c = idx & 3;
    float val = 0.f;
    if (row < 3 && kx < 3 && c < 3)
      val = w1[((r * 32 + oc) * 3 + c) * 9 + row * 3 + kx];
    w1p[t] = f2bf(val);
  } else if (t < 163840) {
    int t2 = t - 16384;
    int j = t2 & 7, lane = (t2 >> 3) & 63;
    int u = t2 >> 9;
    int mt = u & 3; u >>= 2;
    int tap = u % 9;
    int r = u / 9;
    int oc = mt * 16 + (lane & 15);
    int ic = ((lane >> 4) & 3) * 8 + j;
    w2p[t2] = f2bf(w2[((r * 64 + oc) * 32 + ic) * 9 + tap]);
  } else if (t < 753664) {
    int t3 = t - 163840;
    int j = t3 & 7, lane = (t3 >> 3) & 63;
    int u = t3 >> 9;
    int mt = u & 7; u >>= 3;
    int s = u & 1; u >>= 1;
    int tap = u % 9;
    int r = u / 9;
    int oc = mt * 16 + (lane & 15);
    int ic = s * 32 + ((lane >> 4) & 3) * 8 + j;
    w3p[t3] = f2bf(w3[((r * 128 + oc) * 64 + ic) * 9 + tap]);
  } else {
    int th = t - 753664;
    if (th < nhalo) {
      int s = th / 260, i = th - s * 260;
      int y, x;
      if (i < 66) { y = 0; x = i; }
      else if (i < 132) { y = 65; x = i - 66; }
      else {
        int ii = i - 132;
        y = 1 + (ii >> 1);
        x = (ii & 1) ? 65 : 0;
      }
      short8 z = {0, 0, 0, 0, 0, 0, 0, 0};
      *(short8*)(h2p + ((size_t)s * 66 * 66 + y * 66 + x) * 8) = z;
    }
  }
}

// FUSED conv1+conv2, 2-out-row blocks, single-phase img staging.
// Block = conv2 out 2 rows x 32 px. Grid (xh 2, yg 32, sample 128). 256 thr.
// h1 tile: hy 0..4 <-> real h1 row 2*oy0-1+hy; lx 0..65 <-> real px xh*64-1+lx.
// img tile row t 0..10 <-> real img row 4*oy0-3+t; col tc <-> (xh*128-3)+tc.
// Waves: conv1 row hy=wv (wave 0 also hy=4); conv2 (row wv>>1, px-half wv&1).
__global__ __launch_bounds__(256, 4) void conv12b_k(
    const float* __restrict__ img, const unsigned short* __restrict__ w1p,
    const float* __restrict__ b1, const unsigned short* __restrict__ w2p,
    const float* __restrict__ b2, const int* __restrict__ rgn,
    unsigned short* __restrict__ outp, int b0) {
  __shared__ unsigned short imgT[11 * 168 * 4];  // 14,784 B
  __shared__ unsigned short h1T[5 * 4 * 66 * 8]; // 21,120 B
  __shared__ float sB1[32];
  __shared__ float sB2[64];
  const int tid = threadIdx.x;
  const int xh = blockIdx.x;        // 0..1
  const int oy0 = blockIdx.y * 2;   // conv2 out row base 0..62
  const int bl = blockIdx.z;
  const int r = __builtin_amdgcn_readfirstlane(rgn[b0 + bl]);
  if (tid < 32) sB1[tid] = b1[r * 32 + tid];
  if (tid >= 64 && tid < 128) sB2[tid - 64] = b2[r * 64 + (tid - 64)];
  const float* ib = img + (size_t)(b0 + bl) * 3 * 65536;
  const int padx = xh ? 65 : 0;          // h1 zero-pad column in this tile
  const bool skiptop = (oy0 == 0);       // hy==0 is real h1 row -1
  const int rb = xh * 128 - 4;           // real img col of chunk elem 0

  const int n = tid & 15, q = (tid >> 4) & 3, wv = tid >> 6;
  const int lane = tid & 63;
  const short8* wpb1 = (const short8*)w1p + (size_t)r * 256 + lane;
  short8 afr1[2][2];
#pragma unroll
  for (int kg = 0; kg < 2; ++kg)
#pragma unroll
    for (int m = 0; m < 2; ++m) afr1[kg][m] = wpb1[(kg * 2 + m) * 64];

  // ---- stage img rows 0..10 (single phase; 451 chunks of 4 px)
  {
    const int nch = 11 * 41;  // 451
    for (int seg = 0; seg < nch; seg += 256) {
      int c = seg + tid;
      if (c < nch) {
        int i = c / 41, cq = c - i * 41;
        int rv = 4 * oy0 - 3 + i;          // real img row (<= 255 always)
        int cb = rb + 4 * cq;              // real img col of chunk elem 0
        unsigned short* dp = &imgT[((size_t)i * 168 + (4 * cq - 1)) * 4];
        if (rv >= 0 && cq > 0 && cb >= 0 && cb + 3 <= 255) {
          const float* p = ib + (size_t)rv * 256 + cb;
          float4v a = *(const float4v*)p;
          float4v bb = *(const float4v*)(p + 65536);
          float4v cc = *(const float4v*)(p + 131072);
#pragma unroll
          for (int e = 0; e < 4; ++e) {
            ushort4v v = {f2bf(a[e]), f2bf(bb[e]), f2bf(cc[e]), 0};
            *(ushort4v*)(dp + e * 4) = v;
          }
        } else {
          for (int e = (cq == 0 ? 1 : 0); e < 4; ++e) {
            int cc2 = cb + e;
            ushort4v v = {0, 0, 0, 0};
            if (rv >= 0 && cc2 >= 0 && cc2 <= 255) {
              const float* p = ib + (size_t)rv * 256 + cc2;
              v.x = f2bf(p[0]);
              v.y = f2bf(p[65536]);
              v.z = f2bf(p[131072]);
            }
            *(ushort4v*)(dp + e * 4) = v;
          }
        }
      }
    }
  }
  // zero h1 pad cells
  {
    short8 z8 = {0, 0, 0, 0, 0, 0, 0, 0};
    if (tid < 20) {  // pad column, all 5 hy x 4 cg
      int hy = tid >> 2, cg = tid & 3;
      *(short8*)&h1T[(((size_t)hy * 4 + cg) * 66 + padx) * 8] = z8;
    }
    if (skiptop) {  // hy==0 row (real h1 row -1)
      for (int c = tid; c < 264; c += 256) {
        int cg = c / 66, x = c - cg * 66;
        *(short8*)&h1T[(((size_t)0 * 4 + cg) * 66 + x) * 8] = z8;
      }
    }
  }
  __syncthreads();

  // ---- conv1: h1 rows hy 0..4 (wave wv does hy=wv; wave 0 also hy=4)
  auto CONV1ROW = [&](int hy) {
    floatx4 a1[5][2];
#pragma unroll
    for (int nt = 0; nt < 5; ++nt)
#pragma unroll
      for (int m = 0; m < 2; ++m) a1[nt][m] = (floatx4){0.f, 0.f, 0.f, 0.f};
#pragma unroll
    for (int kg = 0; kg < 2; ++kg) {
      int row = kg * 2 + (q >> 1);
      int rowc = (row < 3) ? row : 0;  // pad row: zero weights, safe addr
      int tr = 2 * hy + rowc;          // 0..10
#pragma unroll
      for (int nt = 0; nt < 5; ++nt) {
        int lx = nt * 16 + n;          // h1 local px 0..79 (use 0..65)
        short8 bfr = *(const short8*)&imgT[((size_t)tr * 168 + 2 * lx) * 4 +
                                           (q & 1) * 8];
#pragma unroll
        for (int m = 0; m < 2; ++m)
          a1[nt][m] = __builtin_amdgcn_mfma_f32_16x16x32_bf16(
              afr1[kg][m], bfr, a1[nt][m], 0, 0, 0);
      }
    }
#pragma unroll
    for (int nt = 0; nt < 5; ++nt) {
      int lx = nt * 16 + n;
      bool ok = (lx <= 65) && (lx != padx) && !(skiptop && hy == 0);
      if (ok) {
#pragma unroll
        for (int m = 0; m < 2; ++m) {
          ushort4v st;
#pragma unroll
          for (int rr = 0; rr < 4; ++rr) {
            float v = a1[nt][m][rr] + sB1[m * 16 + q * 4 + rr];
            st[rr] = f2bf(v > 0.f ? v : 0.f);
          }
          int cg = m * 2 + (q >> 1);
          *(ushort4v*)&h1T[(((size_t)hy * 4 + cg) * 66 + lx) * 8 +
                           (q & 1) * 4] = st;
        }
      }
    }
  };
  CONV1ROW(wv);
  if (wv == 0) CONV1ROW(4);
  __syncthreads();

  // ---- conv2: wave = (out row wv>>1, px-half wv&1); 16 px x 64 oc
  const int c2r = wv >> 1, c2h = wv & 1;
  const short8* wpb2 = (const short8*)w2p + (size_t)r * 9 * 4 * 64 + lane;
  floatx4 a2[4];
#pragma unroll
  for (int m = 0; m < 4; ++m) a2[m] = (floatx4){0.f, 0.f, 0.f, 0.f};
#pragma unroll
  for (int tap = 0; tap < 9; ++tap) {
    const int ky = tap / 3, kx = tap % 3;
    const int oxl = c2h * 16 + n;  // local out px 0..31
    short8 bf = *(const short8*)&h1T[((((2 * c2r + ky) << 2) + q) * 66 +
                                     (2 * oxl + kx)) * 8];
#pragma unroll
    for (int m = 0; m < 4; ++m) {
      short8 af = wpb2[(tap * 4 + m) * 64];
      a2[m] = __builtin_amdgcn_mfma_f32_16x16x32_bf16(af, bf, a2[m], 0, 0, 0);
    }
  }
  unsigned short* ob = outp + (size_t)bl * 8 * 66 * 66 * 8;
  const int oy = oy0 + c2r;
  const int ox = xh * 32 + c2h * 16 + n;
#pragma unroll
  for (int m = 0; m < 4; ++m) {
    ushort4v st;
#pragma unroll
    for (int rr = 0; rr < 4; ++rr) {
      float v = a2[m][rr] + sB2[m * 16 + q * 4 + rr];
      st[rr] = f2bf(v > 0.f ? v : 0.f);
    }
    int cg = m * 2 + (q >> 1);  // oc/8
    *(ushort4v*)&ob[(((size_t)cg * 66 + oy + 1) * 66 + ox + 1) * 8 +
                    (q & 1) * 4] = st;
  }
}

// conv3 DIRECT, 2 rows/wave (R23-verified). h2p [c8=8][66][66][8] read
// straight from global (L3-resident); weights from w3p (L2).
// Block = 256 thr (4 waves); wave = out rows {2wv, 2wv+1} x 32 px, all
// 128 oc: acc[2][2][8] = 128 regs. Grid (4, 128). Zero mid-kernel barriers.
__global__ __launch_bounds__(256, 2) void conv3dir2_k(
    const unsigned short* __restrict__ in, const unsigned short* __restrict__ wp,
    const float* __restrict__ bias, const int* __restrict__ rgn,
    float* __restrict__ feat, int b0) {
  __shared__ float sBias[128];
  __shared__ float sGap[4 * 128];
  const int tid = threadIdx.x;
  const int bl = blockIdx.y;
  const int b = b0 + bl;
  const int r = __builtin_amdgcn_readfirstlane(rgn[b]);
  if (tid < 128) sBias[tid] = bias[r * 128 + tid];
  const int oyb = blockIdx.x * 8;          // block's first out row (0,8,16,24)
  const unsigned short* gbase = in + (size_t)bl * 8 * 66 * 66 * 8;
  const int lane = tid & 63, wv = tid >> 6;
  const int n = lane & 15, q = (lane >> 4) & 3;
  const short8* wpb = (const short8*)wp + (size_t)r * 9 * 2 * 8 * 64 + lane;

  floatx4 acc[2][2][8];  // [row][nt][m]
#pragma unroll
  for (int r2 = 0; r2 < 2; ++r2)
#pragma unroll
    for (int nt = 0; nt < 2; ++nt)
#pragma unroll
      for (int m = 0; m < 8; ++m) acc[r2][nt][m] = (floatx4){0.f, 0.f, 0.f, 0.f};

#pragma unroll
  for (int s = 0; s < 2; ++s) {
    // activation plane for this wave's q-group: c8 = s*4+q
    const unsigned short* ab = gbase + (size_t)(s * 4 + q) * 66 * 66 * 8;
#pragma unroll
    for (int tap = 0; tap < 9; ++tap) {
      const int ky = tap / 3, kx = tap % 3;
      short8 bfr[2][2];
#pragma unroll
      for (int r2 = 0; r2 < 2; ++r2)
#pragma unroll
        for (int nt = 0; nt < 2; ++nt) {
          int oy = oyb + 2 * wv + r2;      // out row 0..31
          int ox = nt * 16 + n;            // 0..31
          bfr[r2][nt] = *(const short8*)&ab[((size_t)(2 * oy + ky) * 66 +
                                             (2 * ox + kx)) * 8];
        }
      short8 afr[8];
#pragma unroll
      for (int m = 0; m < 8; ++m) afr[m] = wpb[((tap * 2 + s) * 8 + m) * 64];
#pragma unroll
      for (int m = 0; m < 8; ++m)
#pragma unroll
        for (int r2 = 0; r2 < 2; ++r2)
#pragma unroll
          for (int nt = 0; nt < 2; ++nt)
            acc[r2][nt][m] = __builtin_amdgcn_mfma_f32_16x16x32_bf16(
                afr[m], bfr[r2][nt], acc[r2][nt][m], 0, 0, 0);
    }
  }

  // bias + ReLU + GAP over (2 rows x 2 nt x 16 px-lanes), cross-wave combine
#pragma unroll
  for (int m = 0; m < 8; ++m)
#pragma unroll
    for (int rr = 0; rr < 4; ++rr) {
      float bv = sBias[m * 16 + q * 4 + rr];
      float vs = 0.f;
#pragma unroll
      for (int r2 = 0; r2 < 2; ++r2)
#pragma unroll
        for (int nt = 0; nt < 2; ++nt) {
          float v = acc[r2][nt][m][rr] + bv;
          vs += (v > 0.f ? v : 0.f);
        }
      vs += __shfl_xor(vs, 1, 16);
      vs += __shfl_xor(vs, 2, 16);
      vs += __shfl_xor(vs, 4, 16);
      vs += __shfl_xor(vs, 8, 16);
      if (n == 0) sGap[wv * 128 + m * 16 + q * 4 + rr] = vs;
    }
  __syncthreads();
  if (tid < 128)
    atomicAdd(&feat[b * 128 + tid],
              sGap[tid] + sGap[128 + tid] + sGap[256 + tid] + sGap[384 + tid]);
}

// head: 128 samples x 2 classes; float4 loads, dual accumulators (no long
// serial fmaf chain).
__global__ __launch_bounds__(256) void head_k(
    const float* __restrict__ feat, const float* __restrict__ fw,
    const float* __restrict__ fb, const int* __restrict__ rgn,
    float* __restrict__ out) {
  int t = threadIdx.x;
  int b = t >> 1, c = t & 1;
  int r = rgn[b];
  const float4v* fwr = (const float4v*)(fw + (r * 2 + c) * 128);
  const float4v* fv = (const float4v*)(feat + b * 128);
  float4v s0 = {0.f, 0.f, 0.f, 0.f}, s1 = {0.f, 0.f, 0.f, 0.f};
#pragma unroll
  for (int j = 0; j < 32; j += 2) {
    s0 += fwr[j] * fv[j];
    s1 += fwr[j + 1] * fv[j + 1];
  }
  float4v s = s0 + s1;
  float a = (s[0] + s[1]) + (s[2] + s[3]);
  out[t] = a * (1.0f / 1024.0f) + fb[r * 2 + c];
}

extern "C" void kernel_launch(void* const* d_in, const int* in_sizes, int n_in,
                              void* d_out, int out_size, void* d_ws, size_t ws_size,
                              hipStream_t stream) {
  const float* img = (const float*)d_in[0];
  const int* rgn_raw = (const int*)d_in[1];
  const float* w1 = (const float*)d_in[2];
  const float* b1 = (const float*)d_in[3];
  const float* w2 = (const float*)d_in[4];
  const float* b2 = (const float*)d_in[5];
  const float* w3 = (const float*)d_in[6];
  const float* b3 = (const float*)d_in[7];
  const float* fw = (const float*)d_in[8];
  const float* fb = (const float*)d_in[9];
  float* out = (float*)d_out;

  const size_t h2p_s = (size_t)8 * 66 * 66 * 8 * 2;  // 557 KB per sample

  char* ws = (char*)d_ws;
  size_t off = 0;
  auto alloc = [&](size_t bytes) {
    char* p = ws + off;
    off += (bytes + 255) & ~(size_t)255;
    return p;
  };
  unsigned short* h2p = (unsigned short*)alloc((size_t)128 * h2p_s);  // 71 MB
  unsigned short* w1p = (unsigned short*)alloc((size_t)16384 * 2);
  unsigned short* w2p = (unsigned short*)alloc((size_t)147456 * 2);
  unsigned short* w3p = (unsigned short*)alloc((size_t)589824 * 2);
  float* feat = (float*)alloc((size_t)128 * 128 * 4);
  int* rgn = (int*)alloc((size_t)128 * 4);

  // fused setup: prep + pack1 + packT2 + packT3 + h2p halo
  {
    int nhalo = 128 * 8 * 260;
    int total = 753664 + nhalo;
    int nblk = 1 + (total + 255) / 256;
    hipLaunchKernelGGL(setup_k, dim3(nblk), dim3(256), 0, stream,
                       rgn_raw, rgn, feat, w1, w1p, w2, w2p, w3, w3p, h2p, nhalo);
  }

  // conv12: 2-row blocks, grid (2, 32, 128) = 8192 blocks, 4 blocks/CU
  hipLaunchKernelGGL(conv12b_k, dim3(2, 32, 128), dim3(256), 0, stream,
                     img, w1p, b1, w2p, b2, rgn, h2p, 0);
  // conv3 direct, 2 rows/wave: grid (4 row-octets, 128 samples), 256 thr
  hipLaunchKernelGGL(conv3dir2_k, dim3(4, 128), dim3(256), 0, stream,
                     h2p, w3p, b3, rgn, feat, 0);
  hipLaunchKernelGGL(head_k, dim3(1), dim3(256), 0, stream, feat, fw, fb, rgn, out);
}

// Round 14
// 278.167 us; speedup vs baseline: 1.0721x; 1.0721x over previous
//
#include <hip/hip_runtime.h>
#include <cstdint>

// ---------------------------------------------------------------------------
// RegionModel R26: R24 revert + native bf16 cvt (f2bf = 1 instr, was ~5).
// R25 falsified the MLP theory: occupancy 26.8->37.8% but BW flat (1.4 TB/s)
// and dur 104->119 tracking the +15% work — conv12 is throughput-bound, not
// latency-bound. Revert to R24 tile (4 rows x 32 px, 3 blocks/CU, 104us).
// Largest consumer: VALU 30% (~31us), on the critical path in staging
// convert + both epilogues. f2bf was a 4-5 instr manual RTNE dance; gfx950
// has native v_cvt_pk_bf16_f32 (RTNE, bit-identical) — write it as a CAST
// and let the compiler emit cvt (guide m240: don't inline-asm it).
// Predicted: VALUBusy 30 -> ~20%, conv12 104 -> ~90, total ~270.
// conv3dir2 / ballot setup / vectorized head kept from R24.
// ---------------------------------------------------------------------------

typedef __attribute__((ext_vector_type(8))) short short8;
typedef __attribute__((ext_vector_type(4))) float floatx4;
typedef __attribute__((ext_vector_type(4))) unsigned short ushort4v;
typedef __attribute__((ext_vector_type(4))) float float4v;

// fp32 -> bf16 RTNE via native HW cvt (compiler emits v_cvt_pk_bf16_f32).
__device__ inline unsigned short f2bf(float f) {
  return __builtin_bit_cast(unsigned short, (__bf16)f);
}

// Fused setup: block 0 = prep (region decode + feat zero); remaining blocks
// cover pack1 | packT2 | packT3 | h2p halo as one linear index space.
__global__ __launch_bounds__(256) void setup_k(
    const int* __restrict__ rp, int* __restrict__ rout, float* __restrict__ feat,
    const float* __restrict__ w1, unsigned short* __restrict__ w1p,
    const float* __restrict__ w2, unsigned short* __restrict__ w2p,
    const float* __restrict__ w3, unsigned short* __restrict__ w3p,
    unsigned short* __restrict__ h2p, int nhalo) {
  const int tid = threadIdx.x;
  if (blockIdx.x == 0) {
    __shared__ int is64;
    if (tid < 64) {  // wave 0: parallel probe of odd words
      int v = rp[2 * tid + 1];
      unsigned long long ball = __ballot(v != 0);
      if (tid == 0) is64 = (ball == 0ULL) ? 1 : 0;
    }
    __syncthreads();
    if (tid < 128) {
      int r = is64 ? rp[2 * tid] : rp[tid];
      rout[tid] = r & 7;
      float* fr = feat + tid * 128;
      for (int j = 0; j < 128; ++j) fr[j] = 0.f;
    }
    return;
  }
  int t = (blockIdx.x - 1) * 256 + tid;
  if (t < 16384) {
    int j = t & 7, lane = (t >> 3) & 63, mt = (t >> 9) & 1, kg = (t >> 10) & 1,
        r = t >> 11;
    int oc = mt * 16 + (lane & 15);
    int q = (lane >> 4) & 3;
    int row = kg * 2 + (q >> 1);
    int idx = (q & 1) * 8 + j;
    int kx = idx >> 2, c = idx & 3;
    float val = 0.f;
    if (row < 3 && kx < 3 && c < 3)
      val = w1[((r * 32 + oc) * 3 + c) * 9 + row * 3 + kx];
    w1p[t] = f2bf(val);
  } else if (t < 163840) {
    int t2 = t - 16384;
    int j = t2 & 7, lane = (t2 >> 3) & 63;
    int u = t2 >> 9;
    int mt = u & 3; u >>= 2;
    int tap = u % 9;
    int r = u / 9;
    int oc = mt * 16 + (lane & 15);
    int ic = ((lane >> 4) & 3) * 8 + j;
    w2p[t2] = f2bf(w2[((r * 64 + oc) * 32 + ic) * 9 + tap]);
  } else if (t < 753664) {
    int t3 = t - 163840;
    int j = t3 & 7, lane = (t3 >> 3) & 63;
    int u = t3 >> 9;
    int mt = u & 7; u >>= 3;
    int s = u & 1; u >>= 1;
    int tap = u % 9;
    int r = u / 9;
    int oc = mt * 16 + (lane & 15);
    int ic = s * 32 + ((lane >> 4) & 3) * 8 + j;
    w3p[t3] = f2bf(w3[((r * 128 + oc) * 64 + ic) * 9 + tap]);
  } else {
    int th = t - 753664;
    if (th < nhalo) {
      int s = th / 260, i = th - s * 260;
      int y, x;
      if (i < 66) { y = 0; x = i; }
      else if (i < 132) { y = 65; x = i - 66; }
      else {
        int ii = i - 132;
        y = 1 + (ii >> 1);
        x = (ii & 1) ? 65 : 0;
      }
      short8 z = {0, 0, 0, 0, 0, 0, 0, 0};
      *(short8*)(h2p + ((size_t)s * 66 * 66 + y * 66 + x) * 8) = z;
    }
  }
}

// FUSED conv1+conv2, two-phase img staging (R21/R24 form, 104us verified).
// Block = conv2 out 4 rows x 32 px. Grid (xh 2, yg 16, sample 128). 256 thr.
__global__ __launch_bounds__(256, 3) void conv12_k(
    const float* __restrict__ img, const unsigned short* __restrict__ w1p,
    const float* __restrict__ b1, const unsigned short* __restrict__ w2p,
    const float* __restrict__ b2, const int* __restrict__ rgn,
    unsigned short* __restrict__ outp, int b0) {
  __shared__ unsigned short imgT[11 * 168 * 4];  // 14,784 B
  __shared__ unsigned short h1T[9 * 4 * 66 * 8]; // 38,016 B
  __shared__ float sB1[32];
  __shared__ float sB2[64];
  const int tid = threadIdx.x;
  const int xh = blockIdx.x;        // 0..1
  const int oy0 = blockIdx.y * 4;   // conv2 out row base 0..60
  const int bl = blockIdx.z;
  const int r = __builtin_amdgcn_readfirstlane(rgn[b0 + bl]);
  if (tid < 32) sB1[tid] = b1[r * 32 + tid];
  if (tid >= 64 && tid < 128) sB2[tid - 64] = b2[r * 64 + (tid - 64)];
  const float* ib = img + (size_t)(b0 + bl) * 3 * 65536;
  const int padx = xh ? 65 : 0;          // h1 zero-pad column in this tile
  const bool skiptop = (oy0 == 0);       // hy==0 is real h1 row -1
  const int rb = xh * 128 - 4;           // real img col of chunk elem 0

  const int n = tid & 15, q = (tid >> 4) & 3, wv = tid >> 6;
  const int lane = tid & 63;
  const short8* wpb1 = (const short8*)w1p + (size_t)r * 256 + lane;
  short8 afr1[2][2];
#pragma unroll
  for (int kg = 0; kg < 2; ++kg)
#pragma unroll
    for (int m = 0; m < 2; ++m) afr1[kg][m] = wpb1[(kg * 2 + m) * 64];

  // phase-A staging: rows 0..10 -> slots 0..10
  {
    const int nch = 11 * 41;  // 451
    for (int seg = 0; seg < nch; seg += 256) {
      int c = seg + tid;
      if (c < nch) {
        int i = c / 41, cq = c - i * 41;
        int rv = 4 * oy0 - 3 + i;          // real img row
        int cb = rb + 4 * cq;              // real img col of chunk elem 0
        unsigned short* dp = &imgT[((size_t)i * 168 + (4 * cq - 1)) * 4];
        if (rv >= 0 && cq > 0 && cb >= 0 && cb + 3 <= 255) {
          const float* p = ib + (size_t)rv * 256 + cb;
          float4v a = *(const float4v*)p;
          float4v bb = *(const float4v*)(p + 65536);
          float4v cc = *(const float4v*)(p + 131072);
#pragma unroll
          for (int e = 0; e < 4; ++e) {
            ushort4v v = {f2bf(a[e]), f2bf(bb[e]), f2bf(cc[e]), 0};
            *(ushort4v*)(dp + e * 4) = v;
          }
        } else {
          for (int e = (cq == 0 ? 1 : 0); e < 4; ++e) {
            int cc2 = cb + e;
            ushort4v v = {0, 0, 0, 0};
            if (rv >= 0 && cc2 >= 0 && cc2 <= 255) {
              const float* p = ib + (size_t)rv * 256 + cc2;
              v.x = f2bf(p[0]);
              v.y = f2bf(p[65536]);
              v.z = f2bf(p[131072]);
            }
            *(ushort4v*)(dp + e * 4) = v;
          }
        }
      }
    }
  }
  // zero h1 pad cells
  {
    short8 z8 = {0, 0, 0, 0, 0, 0, 0, 0};
    if (tid < 36) {  // pad column, all 9 hy x 4 cg
      int hy = tid / 4, cg = tid % 4;
      *(short8*)&h1T[(((size_t)hy * 4 + cg) * 66 + padx) * 8] = z8;
    }
    if (skiptop) {  // hy==0 row (real h1 row -1)
      for (int c = tid; c < 264; c += 256) {
        int cg = c / 66, x = c - cg * 66;
        *(short8*)&h1T[(((size_t)0 * 4 + cg) * 66 + x) * 8] = z8;
      }
    }
  }

  auto CONV1ROW = [&](int hy, int phaseB) {
    floatx4 a1[5][2];
#pragma unroll
    for (int nt = 0; nt < 5; ++nt)
#pragma unroll
      for (int m = 0; m < 2; ++m) a1[nt][m] = (floatx4){0.f, 0.f, 0.f, 0.f};
#pragma unroll
    for (int kg = 0; kg < 2; ++kg) {
      int row = kg * 2 + (q >> 1);
      int rowc = (row < 3) ? row : 0;  // pad row: zero weights, safe addr
      int tr = 2 * hy + rowc;
      int slot = phaseB ? (tr >= 11 ? tr - 11 : tr) : tr;
#pragma unroll
      for (int nt = 0; nt < 5; ++nt) {
        int lx = nt * 16 + n;          // h1 local px 0..79 (use 0..65)
        short8 bfr = *(const short8*)&imgT[((size_t)slot * 168 + 2 * lx) * 4 +
                                           (q & 1) * 8];
#pragma unroll
        for (int m = 0; m < 2; ++m)
          a1[nt][m] = __builtin_amdgcn_mfma_f32_16x16x32_bf16(
              afr1[kg][m], bfr, a1[nt][m], 0, 0, 0);
      }
    }
#pragma unroll
    for (int nt = 0; nt < 5; ++nt) {
      int lx = nt * 16 + n;
      bool ok = (lx <= 65) && (lx != padx) && !(skiptop && hy == 0);
      if (ok) {
#pragma unroll
        for (int m = 0; m < 2; ++m) {
          ushort4v st;
#pragma unroll
          for (int rr = 0; rr < 4; ++rr) {
            float v = a1[nt][m][rr] + sB1[m * 16 + q * 4 + rr];
            st[rr] = f2bf(v > 0.f ? v : 0.f);
          }
          int cg = m * 2 + (q >> 1);
          *(ushort4v*)&h1T[(((size_t)hy * 4 + cg) * 66 + lx) * 8 +
                           (q & 1) * 4] = st;
        }
      }
    }
  };

  __syncthreads();  // phase-A tile + pads ready

  // T14: issue phase-B fast-path loads (rows 11..18, rv always valid)
  float4v Lb0[3], Lb1[3];
  int ok0 = 0, ok1 = 0;
  {
    int c = tid;  // < 328 always
    int i = c / 41, cq = c - i * 41;
    int cb = rb + 4 * cq;
    if (cq > 0 && cb >= 0 && cb + 3 <= 255) {
      const float* p = ib + (size_t)(4 * oy0 + 8 + i) * 256 + cb;
      Lb0[0] = *(const float4v*)p;
      Lb0[1] = *(const float4v*)(p + 65536);
      Lb0[2] = *(const float4v*)(p + 131072);
      ok0 = 1;
    }
    c = tid + 256;
    if (c < 328) {
      i = c / 41; cq = c - i * 41; cb = rb + 4 * cq;
      if (cq > 0 && cb >= 0 && cb + 3 <= 255) {
        const float* p = ib + (size_t)(4 * oy0 + 8 + i) * 256 + cb;
        Lb1[0] = *(const float4v*)p;
        Lb1[1] = *(const float4v*)(p + 65536);
        Lb1[2] = *(const float4v*)(p + 131072);
        ok1 = 1;
      }
    }
  }

  // conv1 A: hy 0..4
  for (int hy = wv; hy <= 4; hy += 4) CONV1ROW(hy, 0);
  __syncthreads();  // conv1-A img reads done; Lb loads drained

  // STOREB: convert regs -> slots 0..7 (slow edge chunks inline)
  auto STOREB = [&](int c, const float4v* L, int okf) {
    int i = c / 41, cq = c - i * 41;
    int cb = rb + 4 * cq;
    unsigned short* dp = &imgT[((size_t)i * 168 + (4 * cq - 1)) * 4];
    if (okf) {
#pragma unroll
      for (int e = 0; e < 4; ++e) {
        ushort4v v = {f2bf(L[0][e]), f2bf(L[1][e]), f2bf(L[2][e]), 0};
        *(ushort4v*)(dp + e * 4) = v;
      }
    } else {
      int rv = 4 * oy0 + 8 + i;
      for (int e = (cq == 0 ? 1 : 0); e < 4; ++e) {
        int cc2 = cb + e;
        ushort4v v = {0, 0, 0, 0};
        if (cc2 >= 0 && cc2 <= 255) {
          const float* p = ib + (size_t)rv * 256 + cc2;
          v.x = f2bf(p[0]);
          v.y = f2bf(p[65536]);
          v.z = f2bf(p[131072]);
        }
        *(ushort4v*)(dp + e * 4) = v;
      }
    }
  };
  STOREB(tid, Lb0, ok0);
  if (tid + 256 < 328) STOREB(tid + 256, Lb1, ok1);
  __syncthreads();

  // conv1 B: hy 5..8
  CONV1ROW(5 + wv, 1);
  __syncthreads();

  // conv2: out 4 rows x 32 px, 64 oc
  const short8* wpb2 = (const short8*)w2p + (size_t)r * 9 * 4 * 64 + lane;
  floatx4 a2[2][4];
#pragma unroll
  for (int nt = 0; nt < 2; ++nt)
#pragma unroll
    for (int m = 0; m < 4; ++m) a2[nt][m] = (floatx4){0.f, 0.f, 0.f, 0.f};
#pragma unroll
  for (int tap = 0; tap < 9; ++tap) {
    const int ky = tap / 3, kx = tap % 3;
    short8 af[4];
#pragma unroll
    for (int m = 0; m < 4; ++m) af[m] = wpb2[(tap * 4 + m) * 64];
    short8 bf[2];
#pragma unroll
    for (int nt = 0; nt < 2; ++nt) {
      int ox = nt * 16 + n;  // local out px 0..31
      bf[nt] = *(const short8*)&h1T[((((2 * wv + ky) << 2) + q) * 66 +
                                    (2 * ox + kx)) * 8];
    }
#pragma unroll
    for (int m = 0; m < 4; ++m)
#pragma unroll
      for (int nt = 0; nt < 2; ++nt)
        a2[nt][m] = __builtin_amdgcn_mfma_f32_16x16x32_bf16(af[m], bf[nt],
                                                            a2[nt][m], 0, 0, 0);
  }
  unsigned short* ob = outp + (size_t)bl * 8 * 66 * 66 * 8;
  const int oy = oy0 + wv;
#pragma unroll
  for (int nt = 0; nt < 2; ++nt) {
    int ox = xh * 32 + nt * 16 + n;
#pragma unroll
    for (int m = 0; m < 4; ++m) {
      ushort4v st;
#pragma unroll
      for (int rr = 0; rr < 4; ++rr) {
        float v = a2[nt][m][rr] + sB2[m * 16 + q * 4 + rr];
        st[rr] = f2bf(v > 0.f ? v : 0.f);
      }
      int cg = m * 2 + (q >> 1);  // oc/8
      *(ushort4v*)&ob[(((size_t)cg * 66 + oy + 1) * 66 + ox + 1) * 8 +
                      (q & 1) * 4] = st;
    }
  }
}

// conv3 DIRECT, 2 rows/wave (R23-verified). h2p [c8=8][66][66][8] read
// straight from global (L3-resident); weights from w3p (L2).
// Block = 256 thr (4 waves); wave = out rows {2wv, 2wv+1} x 32 px, all
// 128 oc: acc[2][2][8] = 128 regs. Grid (4, 128). Zero mid-kernel barriers.
__global__ __launch_bounds__(256, 2) void conv3dir2_k(
    const unsigned short* __restrict__ in, const unsigned short* __restrict__ wp,
    const float* __restrict__ bias, const int* __restrict__ rgn,
    float* __restrict__ feat, int b0) {
  __shared__ float sBias[128];
  __shared__ float sGap[4 * 128];
  const int tid = threadIdx.x;
  const int bl = blockIdx.y;
  const int b = b0 + bl;
  const int r = __builtin_amdgcn_readfirstlane(rgn[b]);
  if (tid < 128) sBias[tid] = bias[r * 128 + tid];
  const int oyb = blockIdx.x * 8;          // block's first out row (0,8,16,24)
  const unsigned short* gbase = in + (size_t)bl * 8 * 66 * 66 * 8;
  const int lane = tid & 63, wv = tid >> 6;
  const int n = lane & 15, q = (lane >> 4) & 3;
  const short8* wpb = (const short8*)wp + (size_t)r * 9 * 2 * 8 * 64 + lane;

  floatx4 acc[2][2][8];  // [row][nt][m]
#pragma unroll
  for (int r2 = 0; r2 < 2; ++r2)
#pragma unroll
    for (int nt = 0; nt < 2; ++nt)
#pragma unroll
      for (int m = 0; m < 8; ++m) acc[r2][nt][m] = (floatx4){0.f, 0.f, 0.f, 0.f};

#pragma unroll
  for (int s = 0; s < 2; ++s) {
    // activation plane for this wave's q-group: c8 = s*4+q
    const unsigned short* ab = gbase + (size_t)(s * 4 + q) * 66 * 66 * 8;
#pragma unroll
    for (int tap = 0; tap < 9; ++tap) {
      const int ky = tap / 3, kx = tap % 3;
      short8 bfr[2][2];
#pragma unroll
      for (int r2 = 0; r2 < 2; ++r2)
#pragma unroll
        for (int nt = 0; nt < 2; ++nt) {
          int oy = oyb + 2 * wv + r2;      // out row 0..31
          int ox = nt * 16 + n;            // 0..31
          bfr[r2][nt] = *(const short8*)&ab[((size_t)(2 * oy + ky) * 66 +
                                             (2 * ox + kx)) * 8];
        }
      short8 afr[8];
#pragma unroll
      for (int m = 0; m < 8; ++m) afr[m] = wpb[((tap * 2 + s) * 8 + m) * 64];
#pragma unroll
      for (int m = 0; m < 8; ++m)
#pragma unroll
        for (int r2 = 0; r2 < 2; ++r2)
#pragma unroll
          for (int nt = 0; nt < 2; ++nt)
            acc[r2][nt][m] = __builtin_amdgcn_mfma_f32_16x16x32_bf16(
                afr[m], bfr[r2][nt], acc[r2][nt][m], 0, 0, 0);
    }
  }

  // bias + ReLU + GAP over (2 rows x 2 nt x 16 px-lanes), cross-wave combine
#pragma unroll
  for (int m = 0; m < 8; ++m)
#pragma unroll
    for (int rr = 0; rr < 4; ++rr) {
      float bv = sBias[m * 16 + q * 4 + rr];
      float vs = 0.f;
#pragma unroll
      for (int r2 = 0; r2 < 2; ++r2)
#pragma unroll
        for (int nt = 0; nt < 2; ++nt) {
          float v = acc[r2][nt][m][rr] + bv;
          vs += (v > 0.f ? v : 0.f);
        }
      vs += __shfl_xor(vs, 1, 16);
      vs += __shfl_xor(vs, 2, 16);
      vs += __shfl_xor(vs, 4, 16);
      vs += __shfl_xor(vs, 8, 16);
      if (n == 0) sGap[wv * 128 + m * 16 + q * 4 + rr] = vs;
    }
  __syncthreads();
  if (tid < 128)
    atomicAdd(&feat[b * 128 + tid],
              sGap[tid] + sGap[128 + tid] + sGap[256 + tid] + sGap[384 + tid]);
}

// head: 128 samples x 2 classes; float4 loads, dual accumulators.
__global__ __launch_bounds__(256) void head_k(
    const float* __restrict__ feat, const float* __restrict__ fw,
    const float* __restrict__ fb, const int* __restrict__ rgn,
    float* __restrict__ out) {
  int t = threadIdx.x;
  int b = t >> 1, c = t & 1;
  int r = rgn[b];
  const float4v* fwr = (const float4v*)(fw + (r * 2 + c) * 128);
  const float4v* fv = (const float4v*)(feat + b * 128);
  float4v s0 = {0.f, 0.f, 0.f, 0.f}, s1 = {0.f, 0.f, 0.f, 0.f};
#pragma unroll
  for (int j = 0; j < 32; j += 2) {
    s0 += fwr[j] * fv[j];
    s1 += fwr[j + 1] * fv[j + 1];
  }
  float4v s = s0 + s1;
  float a = (s[0] + s[1]) + (s[2] + s[3]);
  out[t] = a * (1.0f / 1024.0f) + fb[r * 2 + c];
}

extern "C" void kernel_launch(void* const* d_in, const int* in_sizes, int n_in,
                              void* d_out, int out_size, void* d_ws, size_t ws_size,
                              hipStream_t stream) {
  const float* img = (const float*)d_in[0];
  const int* rgn_raw = (const int*)d_in[1];
  const float* w1 = (const float*)d_in[2];
  const float* b1 = (const float*)d_in[3];
  const float* w2 = (const float*)d_in[4];
  const float* b2 = (const float*)d_in[5];
  const float* w3 = (const float*)d_in[6];
  const float* b3 = (const float*)d_in[7];
  const float* fw = (const float*)d_in[8];
  const float* fb = (const float*)d_in[9];
  float* out = (float*)d_out;

  const size_t h2p_s = (size_t)8 * 66 * 66 * 8 * 2;  // 557 KB per sample

  char* ws = (char*)d_ws;
  size_t off = 0;
  auto alloc = [&](size_t bytes) {
    char* p = ws + off;
    off += (bytes + 255) & ~(size_t)255;
    return p;
  };
  unsigned short* h2p = (unsigned short*)alloc((size_t)128 * h2p_s);  // 71 MB
  unsigned short* w1p = (unsigned short*)alloc((size_t)16384 * 2);
  unsigned short* w2p = (unsigned short*)alloc((size_t)147456 * 2);
  unsigned short* w3p = (unsigned short*)alloc((size_t)589824 * 2);
  float* feat = (float*)alloc((size_t)128 * 128 * 4);
  int* rgn = (int*)alloc((size_t)128 * 4);

  // fused setup: prep + pack1 + packT2 + packT3 + h2p halo
  {
    int nhalo = 128 * 8 * 260;
    int total = 753664 + nhalo;
    int nblk = 1 + (total + 255) / 256;
    hipLaunchKernelGGL(setup_k, dim3(nblk), dim3(256), 0, stream,
                       rgn_raw, rgn, feat, w1, w1p, w2, w2p, w3, w3p, h2p, nhalo);
  }

  // conv12: single full-batch dispatch (4096 blocks, R24-verified tile)
  hipLaunchKernelGGL(conv12_k, dim3(2, 16, 128), dim3(256), 0, stream,
                     img, w1p, b1, w2p, b2, rgn, h2p, 0);
  // conv3 direct, 2 rows/wave: grid (4 row-octets, 128 samples), 256 thr
  hipLaunchKernelGGL(conv3dir2_k, dim3(4, 128), dim3(256), 0, stream,
                     h2p, w3p, b3, rgn, feat, 0);
  hipLaunchKernelGGL(head_k, dim3(1), dim3(256), 0, stream, feat, fw, fb, rgn, out);
}

// Round 15
// 260.463 us; speedup vs baseline: 1.1450x; 1.0680x over previous
//
#include <hip/hip_runtime.h>
#include <cstdint>

// ---------------------------------------------------------------------------
// RegionModel R27: conv3 weights staged in LDS (shared by 4 waves).
// R26 = 278us best (conv12 99us after native cvt). conv3 evidence (R23:
// halving weight re-reads/MFMA gave ~30us) fingerprints it weight-load
// bound: each wave streams 147KB of w3p from L2 on the MFMA chain.
// R27 conv3w_k: per K-half s, stage the 73.7KB weight slice once via g2l16
// (18 rounds x 256 thr), 9-tap loop reads afr from LDS b128 (lane stride
// 16B = 2-way, free). Per-wave global loads 216 -> 72 (activations only);
// block L2 weight traffic 8x down. LDS 76.3KB -> 2 blocks/CU (unchanged).
// conv12 / setup / head unchanged (controls). Predicted total ~255-266.
// ---------------------------------------------------------------------------

typedef __attribute__((ext_vector_type(8))) short short8;
typedef __attribute__((ext_vector_type(4))) float floatx4;
typedef __attribute__((ext_vector_type(4))) unsigned short ushort4v;
typedef __attribute__((ext_vector_type(4))) float float4v;

// fp32 -> bf16 RTNE via native HW cvt (compiler emits v_cvt_pk_bf16_f32).
__device__ inline unsigned short f2bf(float f) {
  return __builtin_bit_cast(unsigned short, (__bf16)f);
}

// Async 16B global->LDS DMA. LDS dest = wave-uniform base + lane*16.
__device__ inline void g2l16(const unsigned short* g, unsigned short* l) {
  __builtin_amdgcn_global_load_lds(
      (const __attribute__((address_space(1))) unsigned int*)g,
      (__attribute__((address_space(3))) unsigned int*)(unsigned int)(uintptr_t)l,
      16, 0, 0);
}

// Fused setup: block 0 = prep (region decode + feat zero); remaining blocks
// cover pack1 | packT2 | packT3 | h2p halo as one linear index space.
__global__ __launch_bounds__(256) void setup_k(
    const int* __restrict__ rp, int* __restrict__ rout, float* __restrict__ feat,
    const float* __restrict__ w1, unsigned short* __restrict__ w1p,
    const float* __restrict__ w2, unsigned short* __restrict__ w2p,
    const float* __restrict__ w3, unsigned short* __restrict__ w3p,
    unsigned short* __restrict__ h2p, int nhalo) {
  const int tid = threadIdx.x;
  if (blockIdx.x == 0) {
    __shared__ int is64;
    if (tid < 64) {  // wave 0: parallel probe of odd words
      int v = rp[2 * tid + 1];
      unsigned long long ball = __ballot(v != 0);
      if (tid == 0) is64 = (ball == 0ULL) ? 1 : 0;
    }
    __syncthreads();
    if (tid < 128) {
      int r = is64 ? rp[2 * tid] : rp[tid];
      rout[tid] = r & 7;
      float* fr = feat + tid * 128;
      for (int j = 0; j < 128; ++j) fr[j] = 0.f;
    }
    return;
  }
  int t = (blockIdx.x - 1) * 256 + tid;
  if (t < 16384) {
    int j = t & 7, lane = (t >> 3) & 63, mt = (t >> 9) & 1, kg = (t >> 10) & 1,
        r = t >> 11;
    int oc = mt * 16 + (lane & 15);
    int q = (lane >> 4) & 3;
    int row = kg * 2 + (q >> 1);
    int idx = (q & 1) * 8 + j;
    int kx = idx >> 2, c = idx & 3;
    float val = 0.f;
    if (row < 3 && kx < 3 && c < 3)
      val = w1[((r * 32 + oc) * 3 + c) * 9 + row * 3 + kx];
    w1p[t] = f2bf(val);
  } else if (t < 163840) {
    int t2 = t - 16384;
    int j = t2 & 7, lane = (t2 >> 3) & 63;
    int u = t2 >> 9;
    int mt = u & 3; u >>= 2;
    int tap = u % 9;
    int r = u / 9;
    int oc = mt * 16 + (lane & 15);
    int ic = ((lane >> 4) & 3) * 8 + j;
    w2p[t2] = f2bf(w2[((r * 64 + oc) * 32 + ic) * 9 + tap]);
  } else if (t < 753664) {
    int t3 = t - 163840;
    int j = t3 & 7, lane = (t3 >> 3) & 63;
    int u = t3 >> 9;
    int mt = u & 7; u >>= 3;
    int s = u & 1; u >>= 1;
    int tap = u % 9;
    int r = u / 9;
    int oc = mt * 16 + (lane & 15);
    int ic = s * 32 + ((lane >> 4) & 3) * 8 + j;
    w3p[t3] = f2bf(w3[((r * 128 + oc) * 64 + ic) * 9 + tap]);
  } else {
    int th = t - 753664;
    if (th < nhalo) {
      int s = th / 260, i = th - s * 260;
      int y, x;
      if (i < 66) { y = 0; x = i; }
      else if (i < 132) { y = 65; x = i - 66; }
      else {
        int ii = i - 132;
        y = 1 + (ii >> 1);
        x = (ii & 1) ? 65 : 0;
      }
      short8 z = {0, 0, 0, 0, 0, 0, 0, 0};
      *(short8*)(h2p + ((size_t)s * 66 * 66 + y * 66 + x) * 8) = z;
    }
  }
}

// FUSED conv1+conv2, two-phase img staging (R26 form, 99us verified).
// Block = conv2 out 4 rows x 32 px. Grid (xh 2, yg 16, sample 128). 256 thr.
__global__ __launch_bounds__(256, 3) void conv12_k(
    const float* __restrict__ img, const unsigned short* __restrict__ w1p,
    const float* __restrict__ b1, const unsigned short* __restrict__ w2p,
    const float* __restrict__ b2, const int* __restrict__ rgn,
    unsigned short* __restrict__ outp, int b0) {
  __shared__ unsigned short imgT[11 * 168 * 4];  // 14,784 B
  __shared__ unsigned short h1T[9 * 4 * 66 * 8]; // 38,016 B
  __shared__ float sB1[32];
  __shared__ float sB2[64];
  const int tid = threadIdx.x;
  const int xh = blockIdx.x;        // 0..1
  const int oy0 = blockIdx.y * 4;   // conv2 out row base 0..60
  const int bl = blockIdx.z;
  const int r = __builtin_amdgcn_readfirstlane(rgn[b0 + bl]);
  if (tid < 32) sB1[tid] = b1[r * 32 + tid];
  if (tid >= 64 && tid < 128) sB2[tid - 64] = b2[r * 64 + (tid - 64)];
  const float* ib = img + (size_t)(b0 + bl) * 3 * 65536;
  const int padx = xh ? 65 : 0;          // h1 zero-pad column in this tile
  const bool skiptop = (oy0 == 0);       // hy==0 is real h1 row -1
  const int rb = xh * 128 - 4;           // real img col of chunk elem 0

  const int n = tid & 15, q = (tid >> 4) & 3, wv = tid >> 6;
  const int lane = tid & 63;
  const short8* wpb1 = (const short8*)w1p + (size_t)r * 256 + lane;
  short8 afr1[2][2];
#pragma unroll
  for (int kg = 0; kg < 2; ++kg)
#pragma unroll
    for (int m = 0; m < 2; ++m) afr1[kg][m] = wpb1[(kg * 2 + m) * 64];

  // phase-A staging: rows 0..10 -> slots 0..10
  {
    const int nch = 11 * 41;  // 451
    for (int seg = 0; seg < nch; seg += 256) {
      int c = seg + tid;
      if (c < nch) {
        int i = c / 41, cq = c - i * 41;
        int rv = 4 * oy0 - 3 + i;          // real img row
        int cb = rb + 4 * cq;              // real img col of chunk elem 0
        unsigned short* dp = &imgT[((size_t)i * 168 + (4 * cq - 1)) * 4];
        if (rv >= 0 && cq > 0 && cb >= 0 && cb + 3 <= 255) {
          const float* p = ib + (size_t)rv * 256 + cb;
          float4v a = *(const float4v*)p;
          float4v bb = *(const float4v*)(p + 65536);
          float4v cc = *(const float4v*)(p + 131072);
#pragma unroll
          for (int e = 0; e < 4; ++e) {
            ushort4v v = {f2bf(a[e]), f2bf(bb[e]), f2bf(cc[e]), 0};
            *(ushort4v*)(dp + e * 4) = v;
          }
        } else {
          for (int e = (cq == 0 ? 1 : 0); e < 4; ++e) {
            int cc2 = cb + e;
            ushort4v v = {0, 0, 0, 0};
            if (rv >= 0 && cc2 >= 0 && cc2 <= 255) {
              const float* p = ib + (size_t)rv * 256 + cc2;
              v.x = f2bf(p[0]);
              v.y = f2bf(p[65536]);
              v.z = f2bf(p[131072]);
            }
            *(ushort4v*)(dp + e * 4) = v;
          }
        }
      }
    }
  }
  // zero h1 pad cells
  {
    short8 z8 = {0, 0, 0, 0, 0, 0, 0, 0};
    if (tid < 36) {  // pad column, all 9 hy x 4 cg
      int hy = tid / 4, cg = tid % 4;
      *(short8*)&h1T[(((size_t)hy * 4 + cg) * 66 + padx) * 8] = z8;
    }
    if (skiptop) {  // hy==0 row (real h1 row -1)
      for (int c = tid; c < 264; c += 256) {
        int cg = c / 66, x = c - cg * 66;
        *(short8*)&h1T[(((size_t)0 * 4 + cg) * 66 + x) * 8] = z8;
      }
    }
  }

  auto CONV1ROW = [&](int hy, int phaseB) {
    floatx4 a1[5][2];
#pragma unroll
    for (int nt = 0; nt < 5; ++nt)
#pragma unroll
      for (int m = 0; m < 2; ++m) a1[nt][m] = (floatx4){0.f, 0.f, 0.f, 0.f};
#pragma unroll
    for (int kg = 0; kg < 2; ++kg) {
      int row = kg * 2 + (q >> 1);
      int rowc = (row < 3) ? row : 0;  // pad row: zero weights, safe addr
      int tr = 2 * hy + rowc;
      int slot = phaseB ? (tr >= 11 ? tr - 11 : tr) : tr;
#pragma unroll
      for (int nt = 0; nt < 5; ++nt) {
        int lx = nt * 16 + n;          // h1 local px 0..79 (use 0..65)
        short8 bfr = *(const short8*)&imgT[((size_t)slot * 168 + 2 * lx) * 4 +
                                           (q & 1) * 8];
#pragma unroll
        for (int m = 0; m < 2; ++m)
          a1[nt][m] = __builtin_amdgcn_mfma_f32_16x16x32_bf16(
              afr1[kg][m], bfr, a1[nt][m], 0, 0, 0);
      }
    }
#pragma unroll
    for (int nt = 0; nt < 5; ++nt) {
      int lx = nt * 16 + n;
      bool ok = (lx <= 65) && (lx != padx) && !(skiptop && hy == 0);
      if (ok) {
#pragma unroll
        for (int m = 0; m < 2; ++m) {
          ushort4v st;
#pragma unroll
          for (int rr = 0; rr < 4; ++rr) {
            float v = a1[nt][m][rr] + sB1[m * 16 + q * 4 + rr];
            st[rr] = f2bf(v > 0.f ? v : 0.f);
          }
          int cg = m * 2 + (q >> 1);
          *(ushort4v*)&h1T[(((size_t)hy * 4 + cg) * 66 + lx) * 8 +
                           (q & 1) * 4] = st;
        }
      }
    }
  };

  __syncthreads();  // phase-A tile + pads ready

  // T14: issue phase-B fast-path loads (rows 11..18, rv always valid)
  float4v Lb0[3], Lb1[3];
  int ok0 = 0, ok1 = 0;
  {
    int c = tid;  // < 328 always
    int i = c / 41, cq = c - i * 41;
    int cb = rb + 4 * cq;
    if (cq > 0 && cb >= 0 && cb + 3 <= 255) {
      const float* p = ib + (size_t)(4 * oy0 + 8 + i) * 256 + cb;
      Lb0[0] = *(const float4v*)p;
      Lb0[1] = *(const float4v*)(p + 65536);
      Lb0[2] = *(const float4v*)(p + 131072);
      ok0 = 1;
    }
    c = tid + 256;
    if (c < 328) {
      i = c / 41; cq = c - i * 41; cb = rb + 4 * cq;
      if (cq > 0 && cb >= 0 && cb + 3 <= 255) {
        const float* p = ib + (size_t)(4 * oy0 + 8 + i) * 256 + cb;
        Lb1[0] = *(const float4v*)p;
        Lb1[1] = *(const float4v*)(p + 65536);
        Lb1[2] = *(const float4v*)(p + 131072);
        ok1 = 1;
      }
    }
  }

  // conv1 A: hy 0..4
  for (int hy = wv; hy <= 4; hy += 4) CONV1ROW(hy, 0);
  __syncthreads();  // conv1-A img reads done; Lb loads drained

  // STOREB: convert regs -> slots 0..7 (slow edge chunks inline)
  auto STOREB = [&](int c, const float4v* L, int okf) {
    int i = c / 41, cq = c - i * 41;
    int cb = rb + 4 * cq;
    unsigned short* dp = &imgT[((size_t)i * 168 + (4 * cq - 1)) * 4];
    if (okf) {
#pragma unroll
      for (int e = 0; e < 4; ++e) {
        ushort4v v = {f2bf(L[0][e]), f2bf(L[1][e]), f2bf(L[2][e]), 0};
        *(ushort4v*)(dp + e * 4) = v;
      }
    } else {
      int rv = 4 * oy0 + 8 + i;
      for (int e = (cq == 0 ? 1 : 0); e < 4; ++e) {
        int cc2 = cb + e;
        ushort4v v = {0, 0, 0, 0};
        if (cc2 >= 0 && cc2 <= 255) {
          const float* p = ib + (size_t)rv * 256 + cc2;
          v.x = f2bf(p[0]);
          v.y = f2bf(p[65536]);
          v.z = f2bf(p[131072]);
        }
        *(ushort4v*)(dp + e * 4) = v;
      }
    }
  };
  STOREB(tid, Lb0, ok0);
  if (tid + 256 < 328) STOREB(tid + 256, Lb1, ok1);
  __syncthreads();

  // conv1 B: hy 5..8
  CONV1ROW(5 + wv, 1);
  __syncthreads();

  // conv2: out 4 rows x 32 px, 64 oc
  const short8* wpb2 = (const short8*)w2p + (size_t)r * 9 * 4 * 64 + lane;
  floatx4 a2[2][4];
#pragma unroll
  for (int nt = 0; nt < 2; ++nt)
#pragma unroll
    for (int m = 0; m < 4; ++m) a2[nt][m] = (floatx4){0.f, 0.f, 0.f, 0.f};
#pragma unroll
  for (int tap = 0; tap < 9; ++tap) {
    const int ky = tap / 3, kx = tap % 3;
    short8 af[4];
#pragma unroll
    for (int m = 0; m < 4; ++m) af[m] = wpb2[(tap * 4 + m) * 64];
    short8 bf[2];
#pragma unroll
    for (int nt = 0; nt < 2; ++nt) {
      int ox = nt * 16 + n;  // local out px 0..31
      bf[nt] = *(const short8*)&h1T[((((2 * wv + ky) << 2) + q) * 66 +
                                    (2 * ox + kx)) * 8];
    }
#pragma unroll
    for (int m = 0; m < 4; ++m)
#pragma unroll
      for (int nt = 0; nt < 2; ++nt)
        a2[nt][m] = __builtin_amdgcn_mfma_f32_16x16x32_bf16(af[m], bf[nt],
                                                            a2[nt][m], 0, 0, 0);
  }
  unsigned short* ob = outp + (size_t)bl * 8 * 66 * 66 * 8;
  const int oy = oy0 + wv;
#pragma unroll
  for (int nt = 0; nt < 2; ++nt) {
    int ox = xh * 32 + nt * 16 + n;
#pragma unroll
    for (int m = 0; m < 4; ++m) {
      ushort4v st;
#pragma unroll
      for (int rr = 0; rr < 4; ++rr) {
        float v = a2[nt][m][rr] + sB2[m * 16 + q * 4 + rr];
        st[rr] = f2bf(v > 0.f ? v : 0.f);
      }
      int cg = m * 2 + (q >> 1);  // oc/8
      *(ushort4v*)&ob[(((size_t)cg * 66 + oy + 1) * 66 + ox + 1) * 8 +
                      (q & 1) * 4] = st;
    }
  }
}

// conv3 with LDS-staged WEIGHTS (shared across the block's 4 waves).
// h2p [c8=8][66][66][8] activations read direct from global (L3-resident).
// Per K-half s: stage 73.7KB weight slice once (g2l16, 18 rounds), then
// 9-tap loop reads afr from LDS (b128, lane stride 16B = 2-way = free).
// Block = 256 thr (4 waves); wave = out rows {2wv,2wv+1} x 32 px, 128 oc.
// Per-wave global loads 216 -> 72. Grid (4, 128).
__global__ __launch_bounds__(256, 2) void conv3w_k(
    const unsigned short* __restrict__ in, const unsigned short* __restrict__ wp,
    const float* __restrict__ bias, const int* __restrict__ rgn,
    float* __restrict__ feat, int b0) {
  __shared__ unsigned short wT[9 * 8 * 64 * 8];  // 73,728 B
  __shared__ float sBias[128];
  __shared__ float sGap[4 * 128];
  const int tid = threadIdx.x;
  const int bl = blockIdx.y;
  const int b = b0 + bl;
  const int r = __builtin_amdgcn_readfirstlane(rgn[b]);
  if (tid < 128) sBias[tid] = bias[r * 128 + tid];
  const int oyb = blockIdx.x * 8;          // block's first out row (0,8,16,24)
  const unsigned short* gbase = in + (size_t)bl * 8 * 66 * 66 * 8;
  const int lane = tid & 63, wv = tid >> 6;
  const int n = lane & 15, q = (lane >> 4) & 3;
  const unsigned short* wbase = wp + (size_t)r * 9 * 2 * 8 * 64 * 8;

  floatx4 acc[2][2][8];  // [row][nt][m]
#pragma unroll
  for (int r2 = 0; r2 < 2; ++r2)
#pragma unroll
    for (int nt = 0; nt < 2; ++nt)
#pragma unroll
      for (int m = 0; m < 8; ++m) acc[r2][nt][m] = (floatx4){0.f, 0.f, 0.f, 0.f};

#pragma unroll
  for (int s = 0; s < 2; ++s) {
    if (s) __syncthreads();  // prior K-half's LDS reads done before restage
    // stage weight slice for this s: 4608 chunks of 16B
    for (int seg = 0; seg < 4608; seg += 256) {
      int c = seg + tid;
      int tap = c >> 9, m = (c >> 6) & 7, lc = c & 63;
      const unsigned short* gp =
          wbase + (((size_t)(tap * 2 + s) * 8 + m) * 64 + lc) * 8;
      g2l16(gp, wT + (size_t)(seg + wv * 64) * 8);
    }
    __syncthreads();  // weights ready (vmcnt drained by barrier)

    // activation plane for this wave's q-group: c8 = s*4+q
    const unsigned short* ab = gbase + (size_t)(s * 4 + q) * 66 * 66 * 8;
#pragma unroll
    for (int tap = 0; tap < 9; ++tap) {
      const int ky = tap / 3, kx = tap % 3;
      short8 bfr[2][2];
#pragma unroll
      for (int r2 = 0; r2 < 2; ++r2)
#pragma unroll
        for (int nt = 0; nt < 2; ++nt) {
          int oy = oyb + 2 * wv + r2;      // out row 0..31
          int ox = nt * 16 + n;            // 0..31
          bfr[r2][nt] = *(const short8*)&ab[((size_t)(2 * oy + ky) * 66 +
                                             (2 * ox + kx)) * 8];
        }
      short8 afr[8];
#pragma unroll
      for (int m = 0; m < 8; ++m)
        afr[m] = *(const short8*)&wT[(((size_t)tap * 8 + m) * 64 + lane) * 8];
#pragma unroll
      for (int m = 0; m < 8; ++m)
#pragma unroll
        for (int r2 = 0; r2 < 2; ++r2)
#pragma unroll
          for (int nt = 0; nt < 2; ++nt)
            acc[r2][nt][m] = __builtin_amdgcn_mfma_f32_16x16x32_bf16(
                afr[m], bfr[r2][nt], acc[r2][nt][m], 0, 0, 0);
    }
  }

  // bias + ReLU + GAP over (2 rows x 2 nt x 16 px-lanes), cross-wave combine
#pragma unroll
  for (int m = 0; m < 8; ++m)
#pragma unroll
    for (int rr = 0; rr < 4; ++rr) {
      float bv = sBias[m * 16 + q * 4 + rr];
      float vs = 0.f;
#pragma unroll
      for (int r2 = 0; r2 < 2; ++r2)
#pragma unroll
        for (int nt = 0; nt < 2; ++nt) {
          float v = acc[r2][nt][m][rr] + bv;
          vs += (v > 0.f ? v : 0.f);
        }
      vs += __shfl_xor(vs, 1, 16);
      vs += __shfl_xor(vs, 2, 16);
      vs += __shfl_xor(vs, 4, 16);
      vs += __shfl_xor(vs, 8, 16);
      if (n == 0) sGap[wv * 128 + m * 16 + q * 4 + rr] = vs;
    }
  __syncthreads();
  if (tid < 128)
    atomicAdd(&feat[b * 128 + tid],
              sGap[tid] + sGap[128 + tid] + sGap[256 + tid] + sGap[384 + tid]);
}

// head: 128 samples x 2 classes; float4 loads, dual accumulators.
__global__ __launch_bounds__(256) void head_k(
    const float* __restrict__ feat, const float* __restrict__ fw,
    const float* __restrict__ fb, const int* __restrict__ rgn,
    float* __restrict__ out) {
  int t = threadIdx.x;
  int b = t >> 1, c = t & 1;
  int r = rgn[b];
  const float4v* fwr = (const float4v*)(fw + (r * 2 + c) * 128);
  const float4v* fv = (const float4v*)(feat + b * 128);
  float4v s0 = {0.f, 0.f, 0.f, 0.f}, s1 = {0.f, 0.f, 0.f, 0.f};
#pragma unroll
  for (int j = 0; j < 32; j += 2) {
    s0 += fwr[j] * fv[j];
    s1 += fwr[j + 1] * fv[j + 1];
  }
  float4v s = s0 + s1;
  float a = (s[0] + s[1]) + (s[2] + s[3]);
  out[t] = a * (1.0f / 1024.0f) + fb[r * 2 + c];
}

extern "C" void kernel_launch(void* const* d_in, const int* in_sizes, int n_in,
                              void* d_out, int out_size, void* d_ws, size_t ws_size,
                              hipStream_t stream) {
  const float* img = (const float*)d_in[0];
  const int* rgn_raw = (const int*)d_in[1];
  const float* w1 = (const float*)d_in[2];
  const float* b1 = (const float*)d_in[3];
  const float* w2 = (const float*)d_in[4];
  const float* b2 = (const float*)d_in[5];
  const float* w3 = (const float*)d_in[6];
  const float* b3 = (const float*)d_in[7];
  const float* fw = (const float*)d_in[8];
  const float* fb = (const float*)d_in[9];
  float* out = (float*)d_out;

  const size_t h2p_s = (size_t)8 * 66 * 66 * 8 * 2;  // 557 KB per sample

  char* ws = (char*)d_ws;
  size_t off = 0;
  auto alloc = [&](size_t bytes) {
    char* p = ws + off;
    off += (bytes + 255) & ~(size_t)255;
    return p;
  };
  unsigned short* h2p = (unsigned short*)alloc((size_t)128 * h2p_s);  // 71 MB
  unsigned short* w1p = (unsigned short*)alloc((size_t)16384 * 2);
  unsigned short* w2p = (unsigned short*)alloc((size_t)147456 * 2);
  unsigned short* w3p = (unsigned short*)alloc((size_t)589824 * 2);
  float* feat = (float*)alloc((size_t)128 * 128 * 4);
  int* rgn = (int*)alloc((size_t)128 * 4);

  // fused setup: prep + pack1 + packT2 + packT3 + h2p halo
  {
    int nhalo = 128 * 8 * 260;
    int total = 753664 + nhalo;
    int nblk = 1 + (total + 255) / 256;
    hipLaunchKernelGGL(setup_k, dim3(nblk), dim3(256), 0, stream,
                       rgn_raw, rgn, feat, w1, w1p, w2, w2p, w3, w3p, h2p, nhalo);
  }

  // conv12: single full-batch dispatch (4096 blocks, R26-verified, ~99us)
  hipLaunchKernelGGL(conv12_k, dim3(2, 16, 128), dim3(256), 0, stream,
                     img, w1p, b1, w2p, b2, rgn, h2p, 0);
  // conv3 with LDS-staged weights: grid (4 row-octets, 128 samples), 256 thr
  hipLaunchKernelGGL(conv3w_k, dim3(4, 128), dim3(256), 0, stream,
                     h2p, w3p, b3, rgn, feat, 0);
  hipLaunchKernelGGL(head_k, dim3(1), dim3(256), 0, stream, feat, fw, fb, rgn, out);
}